// Round 6
// baseline (590.111 us; speedup 1.0000x reference)
//
#include <hip/hip_runtime.h>
#include <hip/hip_bf16.h>

typedef unsigned short u16;
typedef unsigned int u32;

using bf16x8 = __bf16 __attribute__((ext_vector_type(8)));
using s16x8  = short  __attribute__((ext_vector_type(8)));
using f32x4  = float  __attribute__((ext_vector_type(4)));

#define DEV static __device__ __forceinline__

constexpr int T_ = 2048, D_ = 1024;
constexpr int C_ = 64, NC_ = 32;   // chunk length / count
constexpr float EPS_ = 1e-5f;

DEV float bf2f(u16 u) { return __uint_as_float(((u32)u) << 16); }
DEV u16 f2bf(float f) {
  u32 u = __float_as_uint(f);
  return (u16)((u + 0x7fffu + ((u >> 16) & 1u)) >> 16);
}
DEV float swishf(float x) { return x / (1.f + __expf(-x)); }
DEV f32x4 zero4() { f32x4 z = {0.f, 0.f, 0.f, 0.f}; return z; }

// fragment loader: operand stored [outdim][contract] row-major, 16B/lane
DEV bf16x8 ld8(const u16* p, int ld, int r0, int k0, int lane) {
  return *(const bf16x8*)(p + (size_t)(r0 + (lane & 15)) * ld +
                          (size_t)(k0 + ((lane >> 4) << 3)));
}
DEV f32x4 MFMA(bf16x8 a, bf16x8 b, f32x4 c) {
  return __builtin_amdgcn_mfma_f32_16x16x32_bf16(a, b, c, 0, 0, 0);
}
// direct global->LDS DMA, 16B per lane; LDS dest = wave-uniform base + lane*16
DEV void gld_lds16(const void* g, void* l) {
  __builtin_amdgcn_global_load_lds(
      (const __attribute__((address_space(1))) unsigned int*)g,
      (__attribute__((address_space(3))) unsigned int*)l, 16, 0, 0);
}

// ---------------- K0: fp32 -> bf16 weight conversion (5 weights fused) ----------------
__global__ __launch_bounds__(256) void k_cvt5(
    const float* __restrict__ s0, const float* __restrict__ s1,
    const float* __restrict__ s2, const float* __restrict__ s3,
    const float* __restrict__ s4, u16* __restrict__ d0, u16* __restrict__ d1,
    u16* __restrict__ d2, u16* __restrict__ d3, u16* __restrict__ d4) {
  const int wsel = blockIdx.x >> 10;
  const float* s = (wsel == 0) ? s0 : (wsel == 1) ? s1 : (wsel == 2) ? s2
                   : (wsel == 3) ? s3 : s4;
  u16* d = (wsel == 0) ? d0 : (wsel == 1) ? d1 : (wsel == 2) ? d2
           : (wsel == 3) ? d3 : d4;
  const int i = (blockIdx.x & 1023) * 256 + threadIdx.x;
  float4 v = ((const float4*)s)[i];
  uint2 o;
  o.x = (u32)f2bf(v.x) | ((u32)f2bf(v.y) << 16);
  o.y = (u32)f2bf(v.z) | ((u32)f2bf(v.w) << 16);
  ((uint2*)d)[i] = o;
}

// ---------------- K1: RMSNorm (fp32 in -> bf16 h) ----------------
__global__ __launch_bounds__(256) void k_rmsnorm(const float* __restrict__ x,
                                                 const float* __restrict__ w,
                                                 u16* __restrict__ h) {
  const int row = blockIdx.x, tid = threadIdx.x;
  float4 v = ((const float4*)(x + (size_t)row * D_))[tid];
  float ss = v.x * v.x + v.y * v.y + v.z * v.z + v.w * v.w;
#pragma unroll
  for (int d = 32; d >= 1; d >>= 1) ss += __shfl_xor(ss, d, 64);
  __shared__ float red[4];
  if ((tid & 63) == 0) red[tid >> 6] = ss;
  __syncthreads();
  float rs = rsqrtf((red[0] + red[1] + red[2] + red[3]) * (1.f / D_) + EPS_);
  float4 wv = ((const float4*)w)[tid];
  uint2 o;
  o.x = (u32)f2bf(v.x * rs * wv.x) | ((u32)f2bf(v.y * rs * wv.y) << 16);
  o.y = (u32)f2bf(v.z * rs * wv.z) | ((u32)f2bf(v.w * rs * wv.w) << 16);
  *(uint2*)(h + (size_t)row * D_ + tid * 4) = o;
}

// ---------------- K6: swish + RMSNorm (bf16 in -> bf16) ----------------
__global__ __launch_bounds__(256) void k_swishnorm(const u16* __restrict__ x,
                                                   const float* __restrict__ w,
                                                   u16* __restrict__ o) {
  const int row = blockIdx.x, tid = threadIdx.x;
  uint2 pk = *(const uint2*)(x + (size_t)row * D_ + tid * 4);
  float v0 = swishf(bf2f((u16)(pk.x & 0xffff))), v1 = swishf(bf2f((u16)(pk.x >> 16)));
  float v2 = swishf(bf2f((u16)(pk.y & 0xffff))), v3 = swishf(bf2f((u16)(pk.y >> 16)));
  float ss = v0 * v0 + v1 * v1 + v2 * v2 + v3 * v3;
#pragma unroll
  for (int d = 32; d >= 1; d >>= 1) ss += __shfl_xor(ss, d, 64);
  __shared__ float red[4];
  if ((tid & 63) == 0) red[tid >> 6] = ss;
  __syncthreads();
  float rs = rsqrtf((red[0] + red[1] + red[2] + red[3]) * (1.f / D_) + EPS_);
  float4 wv = ((const float4*)w)[tid];
  uint2 ov;
  ov.x = (u32)f2bf(v0 * rs * wv.x) | ((u32)f2bf(v1 * rs * wv.y) << 16);
  ov.y = (u32)f2bf(v2 * rs * wv.z) | ((u32)f2bf(v3 * rs * wv.w) << 16);
  *(uint2*)(o + (size_t)row * D_ + tid * 4) = ov;
}

// ---------------- K2/K7: NT GEMM  out = A @ W^T ----------------
// 128x64 tile, BK=32, global_load_lds staging (3 DMA/iter), LINEAR outputs.
// Smaller acc (32 AGPR) + 12KB LDS -> more resident blocks to share DMA latency.
// MODE 0: z selects weight; z<3 -> swish->bf16 (q/k/v); z==3 -> logsigmoid/16 -> f32 linear g
// MODE 1: identity -> fp32 (final projection)
template <int MODE>
__global__ __launch_bounds__(256) void k_gemm(
    const u16* __restrict__ A, const u16* __restrict__ w0,
    const u16* __restrict__ w1, const u16* __restrict__ w2,
    const u16* __restrict__ w3, u16* __restrict__ oq, u16* __restrict__ okk,
    u16* __restrict__ ov, float* __restrict__ og, float* __restrict__ ofin) {
  __shared__ __align__(16) u16 As[128 * 32];
  __shared__ __align__(16) u16 Bs[64 * 32];
  const int z = blockIdx.z;
  const u16* W = (z == 0) ? w0 : (z == 1) ? w1 : (z == 2) ? w2 : w3;
  const int m0 = blockIdx.x * 128, n0 = blockIdx.y * 64;
  const int tid = threadIdx.x, lane = tid & 63, wvi = tid >> 6;
  f32x4 acc[2][4];
#pragma unroll
  for (int i = 0; i < 2; i++)
#pragma unroll
    for (int j = 0; j < 4; j++) acc[i][j] = zero4();
  // staging geometry: one gld_lds16 = 256 lanes x 16B = 64 rows x 32 cols (bf16)
  const int srow = tid >> 2, scb = (tid & 3) * 8;
  const u16* Ag = A + (size_t)(m0 + srow) * 1024 + scb;
  const u16* Wg = W + (size_t)(n0 + srow) * 1024 + scb;
  u16* AsW = As + (wvi * 16) * 32;
  u16* BsW = Bs + (wvi * 16) * 32;
  for (int kk = 0; kk < 1024; kk += 32) {
    gld_lds16(Ag + kk, AsW);
    gld_lds16(Ag + kk + 64 * 1024, AsW + 64 * 32);
    gld_lds16(Wg + kk, BsW);
    __syncthreads();
    bf16x8 af[2], bfr[4];
#pragma unroll
    for (int i = 0; i < 2; i++) af[i] = ld8(As, 32, wvi * 32 + 16 * i, 0, lane);
#pragma unroll
    for (int j = 0; j < 4; j++) bfr[j] = ld8(Bs, 32, 16 * j, 0, lane);
#pragma unroll
    for (int i = 0; i < 2; i++)
#pragma unroll
      for (int j = 0; j < 4; j++) acc[i][j] = MFMA(af[i], bfr[j], acc[i][j]);
    __syncthreads();
  }
  const int q4 = lane >> 4, c15 = lane & 15;
#pragma unroll
  for (int i = 0; i < 2; i++)
#pragma unroll
    for (int j = 0; j < 4; j++)
#pragma unroll
      for (int r = 0; r < 4; r++) {
        int grow = m0 + wvi * 32 + 16 * i + 4 * q4 + r;
        int gcol = n0 + 16 * j + c15;
        size_t idx = (size_t)grow * 1024 + gcol;
        float val = acc[i][j][r];
        if (MODE == 1) {
          ofin[idx] = val;
        } else if (z < 3) {
          u16* o = (z == 0) ? oq : (z == 1) ? okk : ov;
          o[idx] = f2bf(swishf(val));
        } else {
          float g = (val >= 0.f) ? -log1pf(__expf(-val))
                                 : (val - log1pf(__expf(val)));
          og[idx] = g * (1.0f / 16.0f);
        }
      }
}

// ---------------- K2b: gates ----------------
// reads linear g [b,t][h,m]; writes E=exp(Gc) IN PLACE (same elements -> no race),
// U_t [p][c][m][64] bf16 (U = s*exp(-Gc)), Lam [p][c][m].
__global__ __launch_bounds__(256) void k_gates(float* __restrict__ g_inout,
                                               u16* __restrict__ U_t,
                                               float* __restrict__ Lam) {
  const int c = blockIdx.x, p = blockIdx.y, tid = threadIdx.x;  // tid = m
  const int b = p >> 2, hh = p & 3;
  const int R0 = b * T_ + c * C_, hb = hh * 256;
  float ga = 0.f, ea = 1.f;
  short ubuf[C_];
#pragma unroll
  for (int t = 0; t < C_; t++) {
    size_t gi = (size_t)(R0 + t) * D_ + hb + tid;
    float gv = g_inout[gi];
    ga += gv;
    ea = __expf(ga);
    ubuf[t] = (short)f2bf((1.f - __expf(gv)) * __expf(-ga));
    g_inout[gi] = ea;  // E in place
  }
  Lam[((size_t)p * NC_ + c) * 256 + tid] = ea;
  u16* up = U_t + ((size_t)p * NC_ + c) * (256 * C_) + (size_t)tid * C_;
#pragma unroll
  for (int i = 0; i < 8; i++) {
    s16x8 w;
#pragma unroll
    for (int j = 0; j < 8; j++) w[j] = ubuf[i * 8 + j];
    *(s16x8*)(up + i * 8) = w;
  }
}

// ---------------- K3: per-chunk intra states ----------------
// Sk[(p,c)][m][d] = Lam[m] * sum_tau U[tau,m]*k_tau[d]
// Sv[(p,c)][v][m] = Lam[m] * sum_tau U[tau,m]*v_tau[v]
__global__ __launch_bounds__(256) void k_intra(
    const u16* __restrict__ kg, const u16* __restrict__ vg,
    const u16* __restrict__ U_t, const float* __restrict__ Lam,
    u16* __restrict__ Sk, u16* __restrict__ Sv) {
  __shared__ __align__(16) u16 KV[256 * 72];   // K^T then V^T  [d/v][tau]
  __shared__ float LamH[256];
  const int c = blockIdx.x, p = blockIdx.y;
  const int b = p >> 2, hh = p & 3;
  const int R0 = b * T_ + c * C_, hb = hh * 256;
  const int tid = threadIdx.x, lane = tid & 63, wvi = tid >> 6;
  const int q4 = lane >> 4, c15 = lane & 15;
  const size_t chunk = (size_t)p * NC_ + c;
  const u16* Uc = U_t + chunk * (256 * C_);  // [m][64]
  const size_t scBase = chunk * (256 * 256);

  LamH[tid] = Lam[chunk * 256 + tid];
  // stage K^T
  for (int t = 0; t < C_; t++)
    KV[tid * 72 + t] = kg[(size_t)(R0 + t) * D_ + hb + tid];
  __syncthreads();

  // Hk^T: [256 m][256 d]; wave wvi owns m rows [64*wvi, +64)
  for (int cb = 0; cb < 4; cb++) {
    f32x4 acc[4][4];
#pragma unroll
    for (int i = 0; i < 4; i++)
#pragma unroll
      for (int j = 0; j < 4; j++) acc[i][j] = zero4();
#pragma unroll
    for (int ks = 0; ks < 2; ks++) {
      bf16x8 af[4], bfr[4];
#pragma unroll
      for (int i = 0; i < 4; i++) af[i] = ld8(Uc, C_, 64 * wvi + 16 * i, 32 * ks, lane);
#pragma unroll
      for (int j = 0; j < 4; j++) bfr[j] = ld8(KV, 72, 64 * cb + 16 * j, 32 * ks, lane);
#pragma unroll
      for (int i = 0; i < 4; i++)
#pragma unroll
        for (int j = 0; j < 4; j++) acc[i][j] = MFMA(af[i], bfr[j], acc[i][j]);
    }
#pragma unroll
    for (int i = 0; i < 4; i++)
#pragma unroll
      for (int j = 0; j < 4; j++)
#pragma unroll
        for (int r = 0; r < 4; r++) {
          int ml = 64 * wvi + 16 * i + 4 * q4 + r;
          int dd = 64 * cb + 16 * j + c15;
          Sk[scBase + (size_t)ml * 256 + dd] = f2bf(acc[i][j][r] * LamH[ml]);
        }
  }
  __syncthreads();

  // stage V^T
  for (int t = 0; t < C_; t++)
    KV[tid * 72 + t] = vg[(size_t)(R0 + t) * D_ + hb + tid];
  __syncthreads();

  // Hv^T: [256 v][256 m]; wave wvi owns v rows [64*wvi, +64)
  for (int cb = 0; cb < 4; cb++) {
    f32x4 acc[4][4];
#pragma unroll
    for (int i = 0; i < 4; i++)
#pragma unroll
      for (int j = 0; j < 4; j++) acc[i][j] = zero4();
#pragma unroll
    for (int ks = 0; ks < 2; ks++) {
      bf16x8 af[4], bfr[4];
#pragma unroll
      for (int i = 0; i < 4; i++) af[i] = ld8(KV, 72, 64 * wvi + 16 * i, 32 * ks, lane);
#pragma unroll
      for (int j = 0; j < 4; j++) bfr[j] = ld8(Uc, C_, 64 * cb + 16 * j, 32 * ks, lane);
#pragma unroll
      for (int i = 0; i < 4; i++)
#pragma unroll
        for (int j = 0; j < 4; j++) acc[i][j] = MFMA(af[i], bfr[j], acc[i][j]);
    }
#pragma unroll
    for (int i = 0; i < 4; i++)
#pragma unroll
      for (int j = 0; j < 4; j++)
#pragma unroll
        for (int r = 0; r < 4; r++) {
          int vv = 64 * wvi + 16 * i + 4 * q4 + r;
          int ml = 64 * cb + 16 * j + c15;
          Sv[scBase + (size_t)vv * 256 + ml] = f2bf(acc[i][j][r] * LamH[ml]);
        }
  }
}

// ---------------- K4: chunk-prefix scan (entering state per chunk, in place) ----------------
__global__ __launch_bounds__(256) void k_scan(u16* __restrict__ Sk,
                                              u16* __restrict__ Sv,
                                              const float* __restrict__ Lam) {
  const int gid = blockIdx.x * 256 + threadIdx.x;  // 0..262143
  const int st = gid >> 17;
  const int w = gid & 131071;
  const int p = w >> 13;
  const int r = (w >> 5) & 255;
  const int c0 = (w & 31) * 8;
  u16* S = st ? Sv : Sk;
  const size_t base = (size_t)p * NC_ * 65536 + (size_t)r * 256 + c0;
  const float* Lp = Lam + (size_t)p * NC_ * 256;
  float acc[8] = {0, 0, 0, 0, 0, 0, 0, 0};
  for (int c = 0; c < NC_; c++) {
    s16x8 in = *(const s16x8*)(S + base + (size_t)c * 65536);
    s16x8 ov;
#pragma unroll
    for (int j = 0; j < 8; j++) ov[j] = (short)f2bf(acc[j]);
    *(s16x8*)(S + base + (size_t)c * 65536) = ov;  // entering state S_c
    if (st == 0) {
      float lam = Lp[c * 256 + r];
#pragma unroll
      for (int j = 0; j < 8; j++) acc[j] = acc[j] * lam + bf2f((u16)in[j]);
    } else {
#pragma unroll
      for (int j = 0; j < 8; j++) {
        float lam = Lp[c * 256 + c0 + j];
        acc[j] = acc[j] * lam + bf2f((u16)in[j]);
      }
    }
  }
}

// ---------------- K5: per-chunk output ----------------
__global__ __launch_bounds__(256) void k_out(
    const u16* __restrict__ qg, const u16* __restrict__ kg,
    const u16* __restrict__ vg, const u16* __restrict__ U_t,
    const float* __restrict__ Eg, const u16* __restrict__ Sk,
    const u16* __restrict__ Sv, u16* __restrict__ orw) {
  __shared__ __align__(16) char lds[61440];
  u16* As = (u16*)lds;                // [64][72]: masked QK^T, later W
  u16* Pt = (u16*)(lds + 9216);       // [64][264]: P~
  u16* UnH = (u16*)(lds + 43008);     // [64][132]: U^T half (P5)
  u16* VxH = (u16*)(lds + 43008);     // [128][72]: V^T half (P6)

  const int c = blockIdx.x, p = blockIdx.y;
  const int b = p >> 2, hh = p & 3;
  const int R0 = b * T_ + c * C_, hb = hh * 256;
  const int tid = threadIdx.x, lane = tid & 63, wvi = tid >> 6;
  const int q4 = lane >> 4, c15 = lane & 15;
  const u16* qbase = qg + (size_t)R0 * D_ + hb;
  const u16* kbase = kg + (size_t)R0 * D_ + hb;
  const float* Ebase = Eg + (size_t)R0 * D_ + hb;  // E linear [t][1024] window
  const size_t chunk = (size_t)p * NC_ + c;
  const u16* SkC = Sk + chunk * 65536;
  const u16* SvC = Sv + chunk * 65536;
  const u16* Uc = U_t + chunk * (256 * C_);   // [m][64]

  // P1: masked QK^T
  {
    f32x4 acc[4];
#pragma unroll
    for (int n = 0; n < 4; n++) acc[n] = zero4();
#pragma unroll
    for (int ks = 0; ks < 8; ks++) {
      bf16x8 af = ld8(qbase, D_, 16 * wvi, 32 * ks, lane);
#pragma unroll
      for (int n = 0; n < 4; n++)
        acc[n] = MFMA(af, ld8(kbase, D_, 16 * n, 32 * ks, lane), acc[n]);
    }
#pragma unroll
    for (int n = 0; n < 4; n++)
#pragma unroll
      for (int r = 0; r < 4; r++) {
        int t = 16 * wvi + 4 * q4 + r, tau = 16 * n + c15;
        As[t * 72 + tau] = f2bf(tau <= t ? acc[n][r] : 0.f);
      }
  }
  __syncthreads();

  // P2: z = E * (As@U + Q@Sk); E kept in eRg for P3
  f32x4 zac[16], eRg[16];
#pragma unroll
  for (int mh = 0; mh < 2; mh++) {
#pragma unroll
    for (int n = 0; n < 8; n++) zac[mh * 8 + n] = zero4();
#pragma unroll
    for (int ks = 0; ks < 2; ks++) {
      bf16x8 af = ld8(As, 72, 16 * wvi, 32 * ks, lane);
#pragma unroll
      for (int n = 0; n < 8; n++)
        zac[mh * 8 + n] = MFMA(af, ld8(Uc, C_, mh * 128 + 16 * n, 32 * ks, lane),
                               zac[mh * 8 + n]);
    }
#pragma unroll
    for (int ks = 0; ks < 8; ks++) {
      bf16x8 af = ld8(qbase, D_, 16 * wvi, 32 * ks, lane);
#pragma unroll
      for (int n = 0; n < 8; n++)
        zac[mh * 8 + n] = MFMA(
            af, ld8(SkC + (size_t)mh * 128 * 256, 256, 16 * n, 32 * ks, lane),
            zac[mh * 8 + n]);
    }
#pragma unroll
    for (int n = 0; n < 8; n++)
#pragma unroll
      for (int r = 0; r < 4; r++) {
        int t = 16 * wvi + 4 * q4 + r;
        float e = Ebase[(size_t)t * D_ + mh * 128 + 16 * n + c15];
        eRg[mh * 8 + n][r] = e;
        zac[mh * 8 + n][r] *= e;
      }
  }

  // P3: row softmax (16-lane groups) + P~ = p * E
#pragma unroll
  for (int r = 0; r < 4; r++) {
    float mx = -3.0e38f;
#pragma unroll
    for (int i = 0; i < 16; i++) mx = fmaxf(mx, zac[i][r]);
    mx = fmaxf(mx, __shfl_xor(mx, 1, 64));
    mx = fmaxf(mx, __shfl_xor(mx, 2, 64));
    mx = fmaxf(mx, __shfl_xor(mx, 4, 64));
    mx = fmaxf(mx, __shfl_xor(mx, 8, 64));
    float sm = 0.f;
#pragma unroll
    for (int i = 0; i < 16; i++) {
      float e = __expf(zac[i][r] - mx);
      zac[i][r] = e;
      sm += e;
    }
    sm += __shfl_xor(sm, 1, 64);
    sm += __shfl_xor(sm, 2, 64);
    sm += __shfl_xor(sm, 4, 64);
    sm += __shfl_xor(sm, 8, 64);
    float inv = 1.f / sm;
#pragma unroll
    for (int i = 0; i < 16; i++) zac[i][r] *= inv * eRg[i][r];
  }
#pragma unroll
  for (int i = 0; i < 16; i++)
#pragma unroll
    for (int r = 0; r < 4; r++) {
      int t = 16 * wvi + 4 * q4 + r;
      int m = (i >> 3) * 128 + 16 * (i & 7) + c15;
      Pt[t * 264 + m] = f2bf(zac[i][r]);
    }
  __syncthreads();

  // P5: W = mask(P~ @ U^T) -> As   (UnH staged per m-half from U_t)
  {
    f32x4 wac[4];
#pragma unroll
    for (int n = 0; n < 4; n++) wac[n] = zero4();
    for (int mh = 0; mh < 2; mh++) {
      {
        int mloc = tid >> 1, th = tid & 1;
        const u16* ur = Uc + (size_t)(mh * 128 + mloc) * C_ + th * 32;
#pragma unroll
        for (int tt = 0; tt < 4; tt++) {
          s16x8 v = *(const s16x8*)(ur + tt * 8);
#pragma unroll
          for (int j = 0; j < 8; j++)
            UnH[(th * 32 + tt * 8 + j) * 132 + mloc] = (u16)v[j];
        }
      }
      __syncthreads();
#pragma unroll
      for (int ks = 0; ks < 4; ks++) {
        bf16x8 af = ld8(Pt, 264, 16 * wvi, mh * 128 + 32 * ks, lane);
#pragma unroll
        for (int n = 0; n < 4; n++)
          wac[n] = MFMA(af, ld8(UnH, 132, 16 * n, 32 * ks, lane), wac[n]);
      }
      __syncthreads();
    }
#pragma unroll
    for (int n = 0; n < 4; n++)
#pragma unroll
      for (int r = 0; r < 4; r++) {
        int t = 16 * wvi + 4 * q4 + r, tau = 16 * n + c15;
        As[t * 72 + tau] = f2bf(tau <= t ? wac[n][r] : 0.f);
      }
  }
  __syncthreads();

  // P6: o = P~ @ Sv + W @ V^T
  for (int vh = 0; vh < 2; vh++) {
    {
      int vloc = tid >> 1, th = tid & 1;
#pragma unroll 4
      for (int tt = 0; tt < 32; tt++) {
        int t = th * 32 + tt;
        VxH[vloc * 72 + t] = vg[(size_t)(R0 + t) * D_ + hb + vh * 128 + vloc];
      }
    }
    __syncthreads();
    f32x4 oac[8];
#pragma unroll
    for (int n = 0; n < 8; n++) oac[n] = zero4();
#pragma unroll
    for (int ks = 0; ks < 8; ks++) {
      bf16x8 af = ld8(Pt, 264, 16 * wvi, 32 * ks, lane);
#pragma unroll
      for (int n = 0; n < 8; n++)
        oac[n] = MFMA(af, ld8(SvC + (size_t)vh * 128 * 256, 256, 16 * n, 32 * ks, lane), oac[n]);
    }
#pragma unroll
    for (int ks = 0; ks < 2; ks++) {
      bf16x8 af = ld8(As, 72, 16 * wvi, 32 * ks, lane);
#pragma unroll
      for (int n = 0; n < 8; n++)
        oac[n] = MFMA(af, ld8(VxH, 72, 16 * n, 32 * ks, lane), oac[n]);
    }
#pragma unroll
    for (int n = 0; n < 8; n++)
#pragma unroll
      for (int r = 0; r < 4; r++) {
        int t = 16 * wvi + 4 * q4 + r;
        int vc = vh * 128 + 16 * n + c15;
        orw[(size_t)(R0 + t) * D_ + hb + vc] = f2bf(oac[n][r]);
      }
    __syncthreads();
  }
}

extern "C" void kernel_launch(void* const* d_in, const int* in_sizes, int n_in,
                              void* d_out, int out_size, void* d_ws, size_t ws_size,
                              hipStream_t stream) {
  (void)in_sizes; (void)n_in; (void)out_size; (void)ws_size;
  const float* x   = (const float*)d_in[0];
  const float* nw  = (const float*)d_in[1];
  const float* wq  = (const float*)d_in[2];
  const float* wk  = (const float*)d_in[3];
  const float* wvp = (const float*)d_in[4];
  const float* wf  = (const float*)d_in[5];
  const float* gw  = (const float*)d_in[6];
  const float* wo  = (const float*)d_in[7];
  float* out = (float*)d_out;
  char* ws = (char*)d_ws;
  const size_t MB = 1024ull * 1024ull;
  u16*   hbuf = (u16*)(ws);             // 16MB h; later U_t; later o_normed
  u16*   qb   = (u16*)(ws + 16 * MB);   // 16MB
  u16*   kb   = (u16*)(ws + 32 * MB);   // 16MB
  u16*   vb   = (u16*)(ws + 48 * MB);   // 16MB
  float* gb   = (float*)(ws + 64 * MB); // 32MB fp32 linear g -> E in place
  u16*   SkB  = (u16*)(ws + 96 * MB);   // 64MB states [p][c][m][d]
  u16*   SvB  = (u16*)(ws + 160 * MB);  // 64MB states [p][c][v][m]
  float* Lam  = (float*)(ws + 224 * MB);// 0.5MB chunk decays
  u16*   orw  = (u16*)(ws + 226 * MB);  // 16MB raw attention output
  u16*   wqb  = (u16*)(ws + 242 * MB);  // 2MB bf16 weights
  u16*   wkb  = (u16*)(ws + 244 * MB);
  u16*   wvb  = (u16*)(ws + 246 * MB);
  u16*   wfb  = (u16*)(ws + 248 * MB);
  u16*   wob  = (u16*)(ws + 250 * MB);
  u16*   U_t  = hbuf;                   // 16MB [p][c][m][t] bf16 (aliases dead h)

  k_cvt5<<<dim3(5120), dim3(256), 0, stream>>>(wq, wk, wvp, wf, wo,
                                               wqb, wkb, wvb, wfb, wob);
  k_rmsnorm<<<dim3(8192), dim3(256), 0, stream>>>(x, nw, hbuf);
  k_gemm<0><<<dim3(64, 16, 4), dim3(256), 0, stream>>>(
      hbuf, wqb, wkb, wvb, wfb, qb, kb, vb, gb, (float*)nullptr);
  k_gates<<<dim3(NC_, 16), dim3(256), 0, stream>>>(gb, U_t, Lam);
  k_intra<<<dim3(NC_, 16), dim3(256), 0, stream>>>(kb, vb, U_t, Lam, SkB, SvB);
  k_scan<<<dim3(1024), dim3(256), 0, stream>>>(SkB, SvB, Lam);
  k_out<<<dim3(NC_, 16), dim3(256), 0, stream>>>(qb, kb, vb, U_t, gb, SkB, SvB, orw);
  k_swishnorm<<<dim3(8192), dim3(256), 0, stream>>>(orw, gw, hbuf);
  k_gemm<1><<<dim3(64, 16, 1), dim3(256), 0, stream>>>(
      hbuf, wob, wob, wob, wob, (u16*)nullptr, (u16*)nullptr, (u16*)nullptr,
      (float*)nullptr, out);
}

// Round 7
// 483.361 us; speedup vs baseline: 1.2209x; 1.2209x over previous
//
#include <hip/hip_runtime.h>
#include <hip/hip_bf16.h>

typedef unsigned short u16;
typedef unsigned int u32;

using bf16x8 = __bf16 __attribute__((ext_vector_type(8)));
using s16x8  = short  __attribute__((ext_vector_type(8)));
using f32x4  = float  __attribute__((ext_vector_type(4)));

#define DEV static __device__ __forceinline__

constexpr int T_ = 2048, D_ = 1024;
constexpr int C_ = 64, NC_ = 32;   // chunk length / count
constexpr float EPS_ = 1e-5f;

DEV float bf2f(u16 u) { return __uint_as_float(((u32)u) << 16); }
DEV u16 f2bf(float f) {
  u32 u = __float_as_uint(f);
  return (u16)((u + 0x7fffu + ((u >> 16) & 1u)) >> 16);
}
DEV float swishf(float x) { return x / (1.f + __expf(-x)); }
DEV f32x4 zero4() { f32x4 z = {0.f, 0.f, 0.f, 0.f}; return z; }

// fragment loader: operand stored [outdim][contract] row-major, 16B/lane
DEV bf16x8 ld8(const u16* p, int ld, int r0, int k0, int lane) {
  return *(const bf16x8*)(p + (size_t)(r0 + (lane & 15)) * ld +
                          (size_t)(k0 + ((lane >> 4) << 3)));
}
DEV f32x4 MFMA(bf16x8 a, bf16x8 b, f32x4 c) {
  return __builtin_amdgcn_mfma_f32_16x16x32_bf16(a, b, c, 0, 0, 0);
}
// direct global->LDS DMA, 16B per lane; LDS dest = wave-uniform base + lane*16
DEV void gld_lds16(const void* g, void* l) {
  __builtin_amdgcn_global_load_lds(
      (const __attribute__((address_space(1))) unsigned int*)g,
      (__attribute__((address_space(3))) unsigned int*)l, 16, 0, 0);
}

// ---------------- K0: fp32 -> bf16 weight conversion (5 weights fused) ----------------
__global__ __launch_bounds__(256) void k_cvt5(
    const float* __restrict__ s0, const float* __restrict__ s1,
    const float* __restrict__ s2, const float* __restrict__ s3,
    const float* __restrict__ s4, u16* __restrict__ d0, u16* __restrict__ d1,
    u16* __restrict__ d2, u16* __restrict__ d3, u16* __restrict__ d4) {
  const int wsel = blockIdx.x >> 10;
  const float* s = (wsel == 0) ? s0 : (wsel == 1) ? s1 : (wsel == 2) ? s2
                   : (wsel == 3) ? s3 : s4;
  u16* d = (wsel == 0) ? d0 : (wsel == 1) ? d1 : (wsel == 2) ? d2
           : (wsel == 3) ? d3 : d4;
  const int i = (blockIdx.x & 1023) * 256 + threadIdx.x;
  float4 v = ((const float4*)s)[i];
  uint2 o;
  o.x = (u32)f2bf(v.x) | ((u32)f2bf(v.y) << 16);
  o.y = (u32)f2bf(v.z) | ((u32)f2bf(v.w) << 16);
  ((uint2*)d)[i] = o;
}

// ---------------- K1: RMSNorm (fp32 in -> bf16 h) ----------------
__global__ __launch_bounds__(256) void k_rmsnorm(const float* __restrict__ x,
                                                 const float* __restrict__ w,
                                                 u16* __restrict__ h) {
  const int row = blockIdx.x, tid = threadIdx.x;
  float4 v = ((const float4*)(x + (size_t)row * D_))[tid];
  float ss = v.x * v.x + v.y * v.y + v.z * v.z + v.w * v.w;
#pragma unroll
  for (int d = 32; d >= 1; d >>= 1) ss += __shfl_xor(ss, d, 64);
  __shared__ float red[4];
  if ((tid & 63) == 0) red[tid >> 6] = ss;
  __syncthreads();
  float rs = rsqrtf((red[0] + red[1] + red[2] + red[3]) * (1.f / D_) + EPS_);
  float4 wv = ((const float4*)w)[tid];
  uint2 o;
  o.x = (u32)f2bf(v.x * rs * wv.x) | ((u32)f2bf(v.y * rs * wv.y) << 16);
  o.y = (u32)f2bf(v.z * rs * wv.z) | ((u32)f2bf(v.w * rs * wv.w) << 16);
  *(uint2*)(h + (size_t)row * D_ + tid * 4) = o;
}

// ---------------- K6: swish + RMSNorm (bf16 in -> bf16) ----------------
__global__ __launch_bounds__(256) void k_swishnorm(const u16* __restrict__ x,
                                                   const float* __restrict__ w,
                                                   u16* __restrict__ o) {
  const int row = blockIdx.x, tid = threadIdx.x;
  uint2 pk = *(const uint2*)(x + (size_t)row * D_ + tid * 4);
  float v0 = swishf(bf2f((u16)(pk.x & 0xffff))), v1 = swishf(bf2f((u16)(pk.x >> 16)));
  float v2 = swishf(bf2f((u16)(pk.y & 0xffff))), v3 = swishf(bf2f((u16)(pk.y >> 16)));
  float ss = v0 * v0 + v1 * v1 + v2 * v2 + v3 * v3;
#pragma unroll
  for (int d = 32; d >= 1; d >>= 1) ss += __shfl_xor(ss, d, 64);
  __shared__ float red[4];
  if ((tid & 63) == 0) red[tid >> 6] = ss;
  __syncthreads();
  float rs = rsqrtf((red[0] + red[1] + red[2] + red[3]) * (1.f / D_) + EPS_);
  float4 wv = ((const float4*)w)[tid];
  uint2 ov;
  ov.x = (u32)f2bf(v0 * rs * wv.x) | ((u32)f2bf(v1 * rs * wv.y) << 16);
  ov.y = (u32)f2bf(v2 * rs * wv.z) | ((u32)f2bf(v3 * rs * wv.w) << 16);
  *(uint2*)(o + (size_t)row * D_ + tid * 4) = ov;
}

// ---------------- K2: fused 4-weight projection GEMM ----------------
// 128(m) x 64(n) x 4 weights per block; A-tile staged ONCE per K-step.
// w<3 -> swish->bf16 (q/k/v); w==3 -> logsigmoid/16 -> f32 linear g.
__global__ __launch_bounds__(256, 2) void k_gemm4(
    const u16* __restrict__ A, const u16* __restrict__ w0,
    const u16* __restrict__ w1, const u16* __restrict__ w2,
    const u16* __restrict__ w3, u16* __restrict__ oq, u16* __restrict__ okk,
    u16* __restrict__ ov, float* __restrict__ og) {
  __shared__ __align__(16) u16 As[128 * 32];
  __shared__ __align__(16) u16 Bs[4][64 * 32];
  const int m0 = blockIdx.x * 128, n0 = blockIdx.y * 64;
  const int tid = threadIdx.x, lane = tid & 63, wvi = tid >> 6;
  f32x4 acc[4][2][4];  // [weight][mi][nj]
#pragma unroll
  for (int w = 0; w < 4; w++)
#pragma unroll
    for (int i = 0; i < 2; i++)
#pragma unroll
      for (int j = 0; j < 4; j++) acc[w][i][j] = zero4();
  const int srow = tid >> 2, scb = (tid & 3) * 8;
  const u16* Ag = A + (size_t)(m0 + srow) * 1024 + scb;
  const u16* Wg0 = w0 + (size_t)(n0 + srow) * 1024 + scb;
  const u16* Wg1 = w1 + (size_t)(n0 + srow) * 1024 + scb;
  const u16* Wg2 = w2 + (size_t)(n0 + srow) * 1024 + scb;
  const u16* Wg3 = w3 + (size_t)(n0 + srow) * 1024 + scb;
  u16* AsW = As + (wvi * 16) * 32;
  const int bofs = (wvi * 16) * 32;
  for (int kk = 0; kk < 1024; kk += 32) {
    gld_lds16(Ag + kk, AsW);
    gld_lds16(Ag + kk + 64 * 1024, AsW + 64 * 32);
    gld_lds16(Wg0 + kk, Bs[0] + bofs);
    gld_lds16(Wg1 + kk, Bs[1] + bofs);
    gld_lds16(Wg2 + kk, Bs[2] + bofs);
    gld_lds16(Wg3 + kk, Bs[3] + bofs);
    __syncthreads();
    bf16x8 af[2];
#pragma unroll
    for (int i = 0; i < 2; i++) af[i] = ld8(As, 32, wvi * 32 + 16 * i, 0, lane);
#pragma unroll
    for (int w = 0; w < 4; w++) {
      bf16x8 bfr[4];
#pragma unroll
      for (int j = 0; j < 4; j++) bfr[j] = ld8(Bs[w], 32, 16 * j, 0, lane);
#pragma unroll
      for (int i = 0; i < 2; i++)
#pragma unroll
        for (int j = 0; j < 4; j++) acc[w][i][j] = MFMA(af[i], bfr[j], acc[w][i][j]);
    }
    __syncthreads();
  }
  const int q4 = lane >> 4, c15 = lane & 15;
#pragma unroll
  for (int w = 0; w < 4; w++)
#pragma unroll
    for (int i = 0; i < 2; i++)
#pragma unroll
      for (int j = 0; j < 4; j++)
#pragma unroll
        for (int r = 0; r < 4; r++) {
          int grow = m0 + wvi * 32 + 16 * i + 4 * q4 + r;
          int gcol = n0 + 16 * j + c15;
          size_t idx = (size_t)grow * 1024 + gcol;
          float val = acc[w][i][j][r];
          if (w < 3) {
            u16* o = (w == 0) ? oq : (w == 1) ? okk : ov;
            o[idx] = f2bf(swishf(val));
          } else {
            float g = (val >= 0.f) ? -log1pf(__expf(-val))
                                   : (val - log1pf(__expf(val)));
            og[idx] = g * (1.0f / 16.0f);
          }
        }
}

// ---------------- K7: round-3 known-good 128x128 GEMM (final projection) ----------------
__global__ __launch_bounds__(256) void k_gemmO(const u16* __restrict__ A,
                                               const u16* __restrict__ W,
                                               float* __restrict__ ofin) {
  __shared__ __align__(16) u16 As[128 * 32];
  __shared__ __align__(16) u16 Bs[128 * 32];
  const int m0 = blockIdx.x * 128, n0 = blockIdx.y * 128;
  const int tid = threadIdx.x, lane = tid & 63, wvi = tid >> 6;
  const int wr = wvi >> 1, wc = wvi & 1;
  f32x4 acc[4][4];
#pragma unroll
  for (int i = 0; i < 4; i++)
#pragma unroll
    for (int j = 0; j < 4; j++) acc[i][j] = zero4();
  const int srow = tid >> 2, scb = (tid & 3) * 8;
  const u16* Ag = A + (size_t)(m0 + srow) * 1024 + scb;
  const u16* Wg = W + (size_t)(n0 + srow) * 1024 + scb;
  u16* AsW = As + (wvi * 16) * 32;
  u16* BsW = Bs + (wvi * 16) * 32;
  for (int kk = 0; kk < 1024; kk += 32) {
    gld_lds16(Ag + kk, AsW);
    gld_lds16(Ag + kk + 64 * 1024, AsW + 64 * 32);
    gld_lds16(Wg + kk, BsW);
    gld_lds16(Wg + kk + 64 * 1024, BsW + 64 * 32);
    __syncthreads();
    bf16x8 af[4], bfr[4];
#pragma unroll
    for (int i = 0; i < 4; i++) af[i] = ld8(As, 32, wr * 64 + 16 * i, 0, lane);
#pragma unroll
    for (int j = 0; j < 4; j++) bfr[j] = ld8(Bs, 32, wc * 64 + 16 * j, 0, lane);
#pragma unroll
    for (int i = 0; i < 4; i++)
#pragma unroll
      for (int j = 0; j < 4; j++) acc[i][j] = MFMA(af[i], bfr[j], acc[i][j]);
    __syncthreads();
  }
  const int q4 = lane >> 4, c15 = lane & 15;
#pragma unroll
  for (int i = 0; i < 4; i++)
#pragma unroll
    for (int j = 0; j < 4; j++)
#pragma unroll
      for (int r = 0; r < 4; r++) {
        int grow = m0 + wr * 64 + 16 * i + 4 * q4 + r;
        int gcol = n0 + wc * 64 + 16 * j + c15;
        ofin[(size_t)grow * 1024 + gcol] = acc[i][j][r];
      }
}

// ---------------- K2b: gates ----------------
// reads linear g [b,t][h,m]; writes E=exp(Gc) IN PLACE (same elements -> no race),
// U_t [p][c][m][64] bf16 (U = s*exp(-Gc)), Lam [p][c][m].
__global__ __launch_bounds__(256) void k_gates(float* __restrict__ g_inout,
                                               u16* __restrict__ U_t,
                                               float* __restrict__ Lam) {
  const int c = blockIdx.x, p = blockIdx.y, tid = threadIdx.x;  // tid = m
  const int b = p >> 2, hh = p & 3;
  const int R0 = b * T_ + c * C_, hb = hh * 256;
  float ga = 0.f, ea = 1.f;
  short ubuf[C_];
#pragma unroll
  for (int t = 0; t < C_; t++) {
    size_t gi = (size_t)(R0 + t) * D_ + hb + tid;
    float gv = g_inout[gi];
    ga += gv;
    ea = __expf(ga);
    ubuf[t] = (short)f2bf((1.f - __expf(gv)) * __expf(-ga));
    g_inout[gi] = ea;  // E in place
  }
  Lam[((size_t)p * NC_ + c) * 256 + tid] = ea;
  u16* up = U_t + ((size_t)p * NC_ + c) * (256 * C_) + (size_t)tid * C_;
#pragma unroll
  for (int i = 0; i < 8; i++) {
    s16x8 w;
#pragma unroll
    for (int j = 0; j < 8; j++) w[j] = ubuf[i * 8 + j];
    *(s16x8*)(up + i * 8) = w;
  }
}

// ---------------- K3: per-chunk intra states ----------------
__global__ __launch_bounds__(256) void k_intra(
    const u16* __restrict__ kg, const u16* __restrict__ vg,
    const u16* __restrict__ U_t, const float* __restrict__ Lam,
    u16* __restrict__ Sk, u16* __restrict__ Sv) {
  __shared__ __align__(16) u16 KV[256 * 72];   // K^T then V^T  [d/v][tau]
  __shared__ float LamH[256];
  const int c = blockIdx.x, p = blockIdx.y;
  const int b = p >> 2, hh = p & 3;
  const int R0 = b * T_ + c * C_, hb = hh * 256;
  const int tid = threadIdx.x, lane = tid & 63, wvi = tid >> 6;
  const int q4 = lane >> 4, c15 = lane & 15;
  const size_t chunk = (size_t)p * NC_ + c;
  const u16* Uc = U_t + chunk * (256 * C_);  // [m][64]
  const size_t scBase = chunk * (256 * 256);

  LamH[tid] = Lam[chunk * 256 + tid];
  // stage K^T
  for (int t = 0; t < C_; t++)
    KV[tid * 72 + t] = kg[(size_t)(R0 + t) * D_ + hb + tid];
  __syncthreads();

  // Hk^T: [256 m][256 d]; wave wvi owns m rows [64*wvi, +64)
  for (int cb = 0; cb < 4; cb++) {
    f32x4 acc[4][4];
#pragma unroll
    for (int i = 0; i < 4; i++)
#pragma unroll
      for (int j = 0; j < 4; j++) acc[i][j] = zero4();
#pragma unroll
    for (int ks = 0; ks < 2; ks++) {
      bf16x8 af[4], bfr[4];
#pragma unroll
      for (int i = 0; i < 4; i++) af[i] = ld8(Uc, C_, 64 * wvi + 16 * i, 32 * ks, lane);
#pragma unroll
      for (int j = 0; j < 4; j++) bfr[j] = ld8(KV, 72, 64 * cb + 16 * j, 32 * ks, lane);
#pragma unroll
      for (int i = 0; i < 4; i++)
#pragma unroll
        for (int j = 0; j < 4; j++) acc[i][j] = MFMA(af[i], bfr[j], acc[i][j]);
    }
#pragma unroll
    for (int i = 0; i < 4; i++)
#pragma unroll
      for (int j = 0; j < 4; j++)
#pragma unroll
        for (int r = 0; r < 4; r++) {
          int ml = 64 * wvi + 16 * i + 4 * q4 + r;
          int dd = 64 * cb + 16 * j + c15;
          Sk[scBase + (size_t)ml * 256 + dd] = f2bf(acc[i][j][r] * LamH[ml]);
        }
  }
  __syncthreads();

  // stage V^T
  for (int t = 0; t < C_; t++)
    KV[tid * 72 + t] = vg[(size_t)(R0 + t) * D_ + hb + tid];
  __syncthreads();

  // Hv^T: [256 v][256 m]; wave wvi owns v rows [64*wvi, +64)
  for (int cb = 0; cb < 4; cb++) {
    f32x4 acc[4][4];
#pragma unroll
    for (int i = 0; i < 4; i++)
#pragma unroll
      for (int j = 0; j < 4; j++) acc[i][j] = zero4();
#pragma unroll
    for (int ks = 0; ks < 2; ks++) {
      bf16x8 af[4], bfr[4];
#pragma unroll
      for (int i = 0; i < 4; i++) af[i] = ld8(KV, 72, 64 * wvi + 16 * i, 32 * ks, lane);
#pragma unroll
      for (int j = 0; j < 4; j++) bfr[j] = ld8(Uc, C_, 64 * cb + 16 * j, 32 * ks, lane);
#pragma unroll
      for (int i = 0; i < 4; i++)
#pragma unroll
        for (int j = 0; j < 4; j++) acc[i][j] = MFMA(af[i], bfr[j], acc[i][j]);
    }
#pragma unroll
    for (int i = 0; i < 4; i++)
#pragma unroll
      for (int j = 0; j < 4; j++)
#pragma unroll
        for (int r = 0; r < 4; r++) {
          int vv = 64 * wvi + 16 * i + 4 * q4 + r;
          int ml = 64 * cb + 16 * j + c15;
          Sv[scBase + (size_t)vv * 256 + ml] = f2bf(acc[i][j][r] * LamH[ml]);
        }
  }
}

// ---------------- K4: chunk-prefix scan (entering state per chunk, in place) ----------------
__global__ __launch_bounds__(256) void k_scan(u16* __restrict__ Sk,
                                              u16* __restrict__ Sv,
                                              const float* __restrict__ Lam) {
  const int gid = blockIdx.x * 256 + threadIdx.x;  // 0..262143
  const int st = gid >> 17;
  const int w = gid & 131071;
  const int p = w >> 13;
  const int r = (w >> 5) & 255;
  const int c0 = (w & 31) * 8;
  u16* S = st ? Sv : Sk;
  const size_t base = (size_t)p * NC_ * 65536 + (size_t)r * 256 + c0;
  const float* Lp = Lam + (size_t)p * NC_ * 256;
  float acc[8] = {0, 0, 0, 0, 0, 0, 0, 0};
  for (int c = 0; c < NC_; c++) {
    s16x8 in = *(const s16x8*)(S + base + (size_t)c * 65536);
    s16x8 ov;
#pragma unroll
    for (int j = 0; j < 8; j++) ov[j] = (short)f2bf(acc[j]);
    *(s16x8*)(S + base + (size_t)c * 65536) = ov;  // entering state S_c
    if (st == 0) {
      float lam = Lp[c * 256 + r];
#pragma unroll
      for (int j = 0; j < 8; j++) acc[j] = acc[j] * lam + bf2f((u16)in[j]);
    } else {
#pragma unroll
      for (int j = 0; j < 8; j++) {
        float lam = Lp[c * 256 + c0 + j];
        acc[j] = acc[j] * lam + bf2f((u16)in[j]);
      }
    }
  }
}

// ---------------- K5: per-chunk output ----------------
__global__ __launch_bounds__(256) void k_out(
    const u16* __restrict__ qg, const u16* __restrict__ kg,
    const u16* __restrict__ vg, const u16* __restrict__ U_t,
    const float* __restrict__ Eg, const u16* __restrict__ Sk,
    const u16* __restrict__ Sv, u16* __restrict__ orw) {
  __shared__ __align__(16) char lds[61440];
  u16* As = (u16*)lds;                // [64][72]: masked QK^T, later W
  u16* Pt = (u16*)(lds + 9216);       // [64][264]: P~
  u16* UnH = (u16*)(lds + 43008);     // [64][132]: U^T half (P5)
  u16* VxH = (u16*)(lds + 43008);     // [128][72]: V^T half (P6)

  const int c = blockIdx.x, p = blockIdx.y;
  const int b = p >> 2, hh = p & 3;
  const int R0 = b * T_ + c * C_, hb = hh * 256;
  const int tid = threadIdx.x, lane = tid & 63, wvi = tid >> 6;
  const int q4 = lane >> 4, c15 = lane & 15;
  const u16* qbase = qg + (size_t)R0 * D_ + hb;
  const u16* kbase = kg + (size_t)R0 * D_ + hb;
  const float* Ebase = Eg + (size_t)R0 * D_ + hb;  // E linear [t][1024] window
  const size_t chunk = (size_t)p * NC_ + c;
  const u16* SkC = Sk + chunk * 65536;
  const u16* SvC = Sv + chunk * 65536;
  const u16* Uc = U_t + chunk * (256 * C_);   // [m][64]

  // P1: masked QK^T
  {
    f32x4 acc[4];
#pragma unroll
    for (int n = 0; n < 4; n++) acc[n] = zero4();
#pragma unroll
    for (int ks = 0; ks < 8; ks++) {
      bf16x8 af = ld8(qbase, D_, 16 * wvi, 32 * ks, lane);
#pragma unroll
      for (int n = 0; n < 4; n++)
        acc[n] = MFMA(af, ld8(kbase, D_, 16 * n, 32 * ks, lane), acc[n]);
    }
#pragma unroll
    for (int n = 0; n < 4; n++)
#pragma unroll
      for (int r = 0; r < 4; r++) {
        int t = 16 * wvi + 4 * q4 + r, tau = 16 * n + c15;
        As[t * 72 + tau] = f2bf(tau <= t ? acc[n][r] : 0.f);
      }
  }
  __syncthreads();

  // P2: z = E * (As@U + Q@Sk); E kept in eRg for P3
  f32x4 zac[16], eRg[16];
#pragma unroll
  for (int mh = 0; mh < 2; mh++) {
#pragma unroll
    for (int n = 0; n < 8; n++) zac[mh * 8 + n] = zero4();
#pragma unroll
    for (int ks = 0; ks < 2; ks++) {
      bf16x8 af = ld8(As, 72, 16 * wvi, 32 * ks, lane);
#pragma unroll
      for (int n = 0; n < 8; n++)
        zac[mh * 8 + n] = MFMA(af, ld8(Uc, C_, mh * 128 + 16 * n, 32 * ks, lane),
                               zac[mh * 8 + n]);
    }
#pragma unroll
    for (int ks = 0; ks < 8; ks++) {
      bf16x8 af = ld8(qbase, D_, 16 * wvi, 32 * ks, lane);
#pragma unroll
      for (int n = 0; n < 8; n++)
        zac[mh * 8 + n] = MFMA(
            af, ld8(SkC + (size_t)mh * 128 * 256, 256, 16 * n, 32 * ks, lane),
            zac[mh * 8 + n]);
    }
#pragma unroll
    for (int n = 0; n < 8; n++)
#pragma unroll
      for (int r = 0; r < 4; r++) {
        int t = 16 * wvi + 4 * q4 + r;
        float e = Ebase[(size_t)t * D_ + mh * 128 + 16 * n + c15];
        eRg[mh * 8 + n][r] = e;
        zac[mh * 8 + n][r] *= e;
      }
  }

  // P3: row softmax (16-lane groups) + P~ = p * E
#pragma unroll
  for (int r = 0; r < 4; r++) {
    float mx = -3.0e38f;
#pragma unroll
    for (int i = 0; i < 16; i++) mx = fmaxf(mx, zac[i][r]);
    mx = fmaxf(mx, __shfl_xor(mx, 1, 64));
    mx = fmaxf(mx, __shfl_xor(mx, 2, 64));
    mx = fmaxf(mx, __shfl_xor(mx, 4, 64));
    mx = fmaxf(mx, __shfl_xor(mx, 8, 64));
    float sm = 0.f;
#pragma unroll
    for (int i = 0; i < 16; i++) {
      float e = __expf(zac[i][r] - mx);
      zac[i][r] = e;
      sm += e;
    }
    sm += __shfl_xor(sm, 1, 64);
    sm += __shfl_xor(sm, 2, 64);
    sm += __shfl_xor(sm, 4, 64);
    sm += __shfl_xor(sm, 8, 64);
    float inv = 1.f / sm;
#pragma unroll
    for (int i = 0; i < 16; i++) zac[i][r] *= inv * eRg[i][r];
  }
#pragma unroll
  for (int i = 0; i < 16; i++)
#pragma unroll
    for (int r = 0; r < 4; r++) {
      int t = 16 * wvi + 4 * q4 + r;
      int m = (i >> 3) * 128 + 16 * (i & 7) + c15;
      Pt[t * 264 + m] = f2bf(zac[i][r]);
    }
  __syncthreads();

  // P5: W = mask(P~ @ U^T) -> As   (UnH staged per m-half from U_t)
  {
    f32x4 wac[4];
#pragma unroll
    for (int n = 0; n < 4; n++) wac[n] = zero4();
    for (int mh = 0; mh < 2; mh++) {
      {
        int mloc = tid >> 1, th = tid & 1;
        const u16* ur = Uc + (size_t)(mh * 128 + mloc) * C_ + th * 32;
#pragma unroll
        for (int tt = 0; tt < 4; tt++) {
          s16x8 v = *(const s16x8*)(ur + tt * 8);
#pragma unroll
          for (int j = 0; j < 8; j++)
            UnH[(th * 32 + tt * 8 + j) * 132 + mloc] = (u16)v[j];
        }
      }
      __syncthreads();
#pragma unroll
      for (int ks = 0; ks < 4; ks++) {
        bf16x8 af = ld8(Pt, 264, 16 * wvi, mh * 128 + 32 * ks, lane);
#pragma unroll
        for (int n = 0; n < 4; n++)
          wac[n] = MFMA(af, ld8(UnH, 132, 16 * n, 32 * ks, lane), wac[n]);
      }
      __syncthreads();
    }
#pragma unroll
    for (int n = 0; n < 4; n++)
#pragma unroll
      for (int r = 0; r < 4; r++) {
        int t = 16 * wvi + 4 * q4 + r, tau = 16 * n + c15;
        As[t * 72 + tau] = f2bf(tau <= t ? wac[n][r] : 0.f);
      }
  }
  __syncthreads();

  // P6: o = P~ @ Sv + W @ V^T
  for (int vh = 0; vh < 2; vh++) {
    {
      int vloc = tid >> 1, th = tid & 1;
#pragma unroll 4
      for (int tt = 0; tt < 32; tt++) {
        int t = th * 32 + tt;
        VxH[vloc * 72 + t] = vg[(size_t)(R0 + t) * D_ + hb + vh * 128 + vloc];
      }
    }
    __syncthreads();
    f32x4 oac[8];
#pragma unroll
    for (int n = 0; n < 8; n++) oac[n] = zero4();
#pragma unroll
    for (int ks = 0; ks < 8; ks++) {
      bf16x8 af = ld8(Pt, 264, 16 * wvi, 32 * ks, lane);
#pragma unroll
      for (int n = 0; n < 8; n++)
        oac[n] = MFMA(af, ld8(SvC + (size_t)vh * 128 * 256, 256, 16 * n, 32 * ks, lane), oac[n]);
    }
#pragma unroll
    for (int ks = 0; ks < 2; ks++) {
      bf16x8 af = ld8(As, 72, 16 * wvi, 32 * ks, lane);
#pragma unroll
      for (int n = 0; n < 8; n++)
        oac[n] = MFMA(af, ld8(VxH, 72, 16 * n, 32 * ks, lane), oac[n]);
    }
#pragma unroll
    for (int n = 0; n < 8; n++)
#pragma unroll
      for (int r = 0; r < 4; r++) {
        int t = 16 * wvi + 4 * q4 + r;
        int vc = vh * 128 + 16 * n + c15;
        orw[(size_t)(R0 + t) * D_ + hb + vc] = f2bf(oac[n][r]);
      }
    __syncthreads();
  }
}

extern "C" void kernel_launch(void* const* d_in, const int* in_sizes, int n_in,
                              void* d_out, int out_size, void* d_ws, size_t ws_size,
                              hipStream_t stream) {
  (void)in_sizes; (void)n_in; (void)out_size; (void)ws_size;
  const float* x   = (const float*)d_in[0];
  const float* nw  = (const float*)d_in[1];
  const float* wq  = (const float*)d_in[2];
  const float* wk  = (const float*)d_in[3];
  const float* wvp = (const float*)d_in[4];
  const float* wf  = (const float*)d_in[5];
  const float* gw  = (const float*)d_in[6];
  const float* wo  = (const float*)d_in[7];
  float* out = (float*)d_out;
  char* ws = (char*)d_ws;
  const size_t MB = 1024ull * 1024ull;
  u16*   hbuf = (u16*)(ws);             // 16MB h; later U_t; later o_normed
  u16*   qb   = (u16*)(ws + 16 * MB);   // 16MB
  u16*   kb   = (u16*)(ws + 32 * MB);   // 16MB
  u16*   vb   = (u16*)(ws + 48 * MB);   // 16MB
  float* gb   = (float*)(ws + 64 * MB); // 32MB fp32 linear g -> E in place
  u16*   SkB  = (u16*)(ws + 96 * MB);   // 64MB states [p][c][m][d]
  u16*   SvB  = (u16*)(ws + 160 * MB);  // 64MB states [p][c][v][m]
  float* Lam  = (float*)(ws + 224 * MB);// 0.5MB chunk decays
  u16*   orw  = (u16*)(ws + 226 * MB);  // 16MB raw attention output
  u16*   wqb  = (u16*)(ws + 242 * MB);  // 2MB bf16 weights
  u16*   wkb  = (u16*)(ws + 244 * MB);
  u16*   wvb  = (u16*)(ws + 246 * MB);
  u16*   wfb  = (u16*)(ws + 248 * MB);
  u16*   wob  = (u16*)(ws + 250 * MB);
  u16*   U_t  = hbuf;                   // 16MB [p][c][m][t] bf16 (aliases dead h)

  k_cvt5<<<dim3(5120), dim3(256), 0, stream>>>(wq, wk, wvp, wf, wo,
                                               wqb, wkb, wvb, wfb, wob);
  k_rmsnorm<<<dim3(8192), dim3(256), 0, stream>>>(x, nw, hbuf);
  k_gemm4<<<dim3(64, 16), dim3(256), 0, stream>>>(
      hbuf, wqb, wkb, wvb, wfb, qb, kb, vb, gb);
  k_gates<<<dim3(NC_, 16), dim3(256), 0, stream>>>(gb, U_t, Lam);
  k_intra<<<dim3(NC_, 16), dim3(256), 0, stream>>>(kb, vb, U_t, Lam, SkB, SvB);
  k_scan<<<dim3(1024), dim3(256), 0, stream>>>(SkB, SvB, Lam);
  k_out<<<dim3(NC_, 16), dim3(256), 0, stream>>>(qb, kb, vb, U_t, gb, SkB, SvB, orw);
  k_swishnorm<<<dim3(8192), dim3(256), 0, stream>>>(orw, gw, hbuf);
  k_gemmO<<<dim3(64, 8), dim3(256), 0, stream>>>(hbuf, wob, out);
}